// Round 3
// baseline (332.503 us; speedup 1.0000x reference)
//
#include <hip/hip_runtime.h>
#include <cstddef>

#define WLEN 16384
#define SCALEQ 0.17677669529663687f       // 32^-0.5
#define CB_SCALE 16777216.0f              // 2^24 (keeps C_b out of fp16 subnormals)
#define CB_INV   5.9604644775390625e-08f  // 2^-24

typedef _Float16 half8 __attribute__((ext_vector_type(8)));
typedef _Float16 half4 __attribute__((ext_vector_type(4)));
typedef float float4v __attribute__((ext_vector_type(4)));

// ws float offsets
#define WS_CTX 0         // 16*4*32*32 = 65536 floats (zeroed)
#define WS_DEN 65536     // 16*4*32    = 2048  floats (zeroed)
#define WS_WH  67584     // Wqkv fp16 [384][128] = 49152 halfs = 24576 floats
#define WS_CB  92160     // C_b  fp16 [16][128][128] = 262144 halfs = 131072 floats

#define MFMA16(a, b, c) __builtin_amdgcn_mfma_f32_16x16x32_f16(a, b, c, 0, 0, 0)

// K0: fp32 -> fp16 of W_qkv (layout unchanged: [384 rows][128 c])
__global__ __launch_bounds__(256) void k0_prep(const float* __restrict__ Wqkv,
                                               float* __restrict__ ws) {
  int idx = blockIdx.x * 256 + threadIdx.x;
  _Float16* Wh = (_Float16*)(ws + WS_WH);
  if (idx < 49152) Wh[idx] = (_Float16)Wqkv[idx];
}

// KA: k/v proj (MFMA, A=x so output is n-major) + exp(k) + ctx = ek @ v^T + den
// grid (32 chunks, 16 b), block 256 = 4 waves, wave w <-> head w
// chunk = 512 positions, subtile = 64 positions
__global__ __launch_bounds__(256, 2) void ka_ctx(
    const float* __restrict__ x, float* __restrict__ ws) {
  __shared__ __align__(16) _Float16 xh[64 * 136];      // x^T tile [n][c]
  __shared__ __align__(16) _Float16 ekl[4][32 * 72];   // per-wave [d][n], pad 72
  __shared__ __align__(16) _Float16 vl[4][32 * 72];    // per-wave [e][n], pad 72
  const int tid = threadIdx.x;
  const int lane = tid & 63, wv = tid >> 6;
  const int l15 = lane & 15, quad = lane >> 4;
  const int b = blockIdx.y, chunk = blockIdx.x;
  const _Float16* Wh = (const _Float16*)(ws + WS_WH);
  float* ctx = ws + WS_CTX;
  float* den = ws + WS_DEN;
  const float* xb = x + (size_t)b * 128 * WLEN;

  // B-operand (weights) stationary: nt 0,1 = k rows; 2,3 = v rows
  half8 bw[4][4];
  #pragma unroll
  for (int nt = 0; nt < 4; ++nt) {
    int row = (nt < 2) ? (128 + 32 * wv + nt * 16 + l15)
                       : (256 + 32 * wv + (nt - 2) * 16 + l15);
    #pragma unroll
    for (int ks = 0; ks < 4; ++ks)
      bw[nt][ks] = *(const half8*)(Wh + row * 128 + ks * 32 + quad * 8);
  }

  const float4v zero4 = {0.f, 0.f, 0.f, 0.f};
  float4v ctxa[2][2] = {zero4, zero4, zero4, zero4};
  float denr[2] = {0.f, 0.f};
  const int f = tid & 7, cq = tid >> 3;  // staging: n-quad, c-quad

  for (int s = 0; s < 8; ++s) {
    const int n0 = chunk * 512 + s * 64;
    __syncthreads();
    // stage x fp32 [c][n] -> fp16 transposed [n][c], half4 writes (4 c per write)
    #pragma unroll
    for (int it = 0; it < 2; ++it) {
      const int nn = it * 32 + 4 * f;
      const float* p = xb + (size_t)(4 * cq) * WLEN + n0 + nn;
      float4 r0 = *(const float4*)(p);
      float4 r1 = *(const float4*)(p + WLEN);
      float4 r2 = *(const float4*)(p + 2 * WLEN);
      float4 r3 = *(const float4*)(p + 3 * WLEN);
      float c0[4] = {r0.x, r0.y, r0.z, r0.w};
      float c1[4] = {r1.x, r1.y, r1.z, r1.w};
      float c2[4] = {r2.x, r2.y, r2.z, r2.w};
      float c3[4] = {r3.x, r3.y, r3.z, r3.w};
      #pragma unroll
      for (int i = 0; i < 4; ++i) {
        half4 h;
        h[0] = (_Float16)c0[i]; h[1] = (_Float16)c1[i];
        h[2] = (_Float16)c2[i]; h[3] = (_Float16)c3[i];
        *(half4*)&xh[(nn + i) * 136 + 4 * cq] = h;
      }
    }
    __syncthreads();
    // proj: M=64 n (4 mt), N=64 rows (4 nt), K=128 c
    float4v acc[4][4] = {zero4, zero4, zero4, zero4, zero4, zero4, zero4, zero4,
                         zero4, zero4, zero4, zero4, zero4, zero4, zero4, zero4};
    #pragma unroll
    for (int ks = 0; ks < 4; ++ks) {
      half8 af[4];
      #pragma unroll
      for (int mt = 0; mt < 4; ++mt)
        af[mt] = *(const half8*)&xh[(mt * 16 + l15) * 136 + ks * 32 + quad * 8];
      #pragma unroll
      for (int mt = 0; mt < 4; ++mt)
        #pragma unroll
        for (int nt = 0; nt < 4; ++nt)
          acc[mt][nt] = MFMA16(af[mt], bw[nt][ks], acc[mt][nt]);
    }
    // D[m=n][col]: col=l15 -> d/e index; row=quad*4+r -> n. half4 stores.
    #pragma unroll
    for (int nt = 0; nt < 2; ++nt)
      #pragma unroll
      for (int mt = 0; mt < 4; ++mt) {
        half4 h;
        #pragma unroll
        for (int r = 0; r < 4; ++r) {
          float e = __expf(acc[mt][nt][r]);
          denr[nt] += e;
          h[r] = (_Float16)e;
        }
        *(half4*)&ekl[wv][(nt * 16 + l15) * 72 + mt * 16 + quad * 4] = h;
      }
    #pragma unroll
    for (int et = 0; et < 2; ++et)
      #pragma unroll
      for (int mt = 0; mt < 4; ++mt) {
        half4 h;
        #pragma unroll
        for (int r = 0; r < 4; ++r) h[r] = (_Float16)acc[mt][et + 2][r];
        *(half4*)&vl[wv][(et * 16 + l15) * 72 + mt * 16 + quad * 4] = h;
      }
    // ctx += ek @ v^T : M=32 d, N=32 e, K=64 n (wave-private)
    #pragma unroll
    for (int ks = 0; ks < 2; ++ks) {
      half8 ae[2], bv[2];
      #pragma unroll
      for (int dt = 0; dt < 2; ++dt)
        ae[dt] = *(const half8*)&ekl[wv][(dt * 16 + l15) * 72 + ks * 32 + quad * 8];
      #pragma unroll
      for (int et = 0; et < 2; ++et)
        bv[et] = *(const half8*)&vl[wv][(et * 16 + l15) * 72 + ks * 32 + quad * 8];
      #pragma unroll
      for (int dt = 0; dt < 2; ++dt)
        #pragma unroll
        for (int et = 0; et < 2; ++et)
          ctxa[dt][et] = MFMA16(ae[dt], bv[et], ctxa[dt][et]);
    }
  }
  // reduce to global
  #pragma unroll
  for (int dt = 0; dt < 2; ++dt)
    #pragma unroll
    for (int et = 0; et < 2; ++et)
      #pragma unroll
      for (int r = 0; r < 4; ++r)
        atomicAdd(&ctx[((b * 4 + wv) * 32 + dt * 16 + quad * 4 + r) * 32 +
                       et * 16 + l15],
                  ctxa[dt][et][r]);
  #pragma unroll
  for (int nt = 0; nt < 2; ++nt) {
    float v = denr[nt];
    v += __shfl_xor(v, 16, 64);
    v += __shfl_xor(v, 32, 64);
    if (quad == 0) atomicAdd(&den[(b * 4 + wv) * 32 + nt * 16 + l15], v);
  }
}

// KB: C_b[o][hd] = sum_e Wout[o][h*32+e] * ctx[b,h][d][e]/(den*W), *2^24 -> fp16
__global__ __launch_bounds__(256) void kb_cb(
    const float* __restrict__ Wout, float* __restrict__ ws) {
  __shared__ __align__(16) float nc[4096];
  const int b = blockIdx.x, tid = threadIdx.x;
  const float* ctx = ws + WS_CTX;
  const float* den = ws + WS_DEN;
  _Float16* cb = (_Float16*)(ws + WS_CB) + b * 16384;
  for (int i = tid; i < 4096; i += 256)
    nc[i] = ctx[b * 4096 + i] / (den[b * 128 + (i >> 5)] * 16384.0f);
  __syncthreads();
  const int o = tid >> 1, dh = (tid & 1) * 16;
  for (int h = 0; h < 4; ++h) {
    float wrow[32];
    #pragma unroll
    for (int e4 = 0; e4 < 8; ++e4) {
      float4 w4 = *(const float4*)(Wout + o * 128 + h * 32 + e4 * 4);
      wrow[e4 * 4 + 0] = w4.x; wrow[e4 * 4 + 1] = w4.y;
      wrow[e4 * 4 + 2] = w4.z; wrow[e4 * 4 + 3] = w4.w;
    }
    for (int d = 0; d < 16; ++d) {
      const float* ncr = &nc[(h * 32 + dh + d) * 32];
      float acc = 0.f;
      #pragma unroll
      for (int e = 0; e < 32; ++e) acc += wrow[e] * ncr[e];
      cb[o * 128 + h * 32 + dh + d] = (_Float16)(acc * CB_SCALE);
    }
  }
}

// KC: q-proj MFMA -> softmax -> LDS roundtrip -> y^T = q^T @ C_b^T (B from L2)
//     -> +b_out -> channel LN via lane shuffles -> float4 stores
// grid (128 tiles, 16 b), block 256 = 4 waves; wave w: head w (ph1), n-strip w (ph2)
__global__ __launch_bounds__(256, 2) void kc_out(
    const float* __restrict__ x, const float* __restrict__ wsc,
    const float* __restrict__ b_out, const float* __restrict__ gamma,
    const float* __restrict__ beta, float* __restrict__ out) {
  __shared__ __align__(16) _Float16 xh[128 * 136];  // x^T tile, reused as q_l[n][hd]
  const int tid = threadIdx.x;
  const int lane = tid & 63, wv = tid >> 6;
  const int l15 = lane & 15, quad = lane >> 4;
  const int b = blockIdx.y, tile = blockIdx.x;
  const int n0 = tile * 128;
  const _Float16* Wh = (const _Float16*)(wsc + WS_WH);
  const _Float16* cbg = (const _Float16*)(wsc + WS_CB) + b * 16384;
  const float* xb = x + (size_t)b * 128 * WLEN;
  const float4v zero4 = {0.f, 0.f, 0.f, 0.f};

  // phase-1 A-frags: q rows 32*wv .. +31 (head wv), stationary
  half8 a1[2][4];
  #pragma unroll
  for (int mt = 0; mt < 2; ++mt)
    #pragma unroll
    for (int ks = 0; ks < 4; ++ks)
      a1[mt][ks] = *(const half8*)(Wh + (32 * wv + mt * 16 + l15) * 128 +
                                   ks * 32 + quad * 8);

  // stage x fp32 [c][n] -> fp16 [n][c], half4 writes
  const int f = tid & 7, cq = tid >> 3;
  #pragma unroll
  for (int it = 0; it < 4; ++it) {
    const int nn = it * 32 + 4 * f;
    const float* p = xb + (size_t)(4 * cq) * WLEN + n0 + nn;
    float4 r0 = *(const float4*)(p);
    float4 r1 = *(const float4*)(p + WLEN);
    float4 r2 = *(const float4*)(p + 2 * WLEN);
    float4 r3 = *(const float4*)(p + 3 * WLEN);
    float c0[4] = {r0.x, r0.y, r0.z, r0.w};
    float c1[4] = {r1.x, r1.y, r1.z, r1.w};
    float c2[4] = {r2.x, r2.y, r2.z, r2.w};
    float c3[4] = {r3.x, r3.y, r3.z, r3.w};
    #pragma unroll
    for (int i = 0; i < 4; ++i) {
      half4 h;
      h[0] = (_Float16)c0[i]; h[1] = (_Float16)c1[i];
      h[2] = (_Float16)c2[i]; h[3] = (_Float16)c3[i];
      *(half4*)&xh[(nn + i) * 136 + 4 * cq] = h;
    }
  }
  __syncthreads();

  // phase 1: q_raw = Wq @ x : per wave M=32 (head rows), N=128 n, K=128 c
  float4v acc[2][8] = {zero4, zero4, zero4, zero4, zero4, zero4, zero4, zero4,
                       zero4, zero4, zero4, zero4, zero4, zero4, zero4, zero4};
  #pragma unroll
  for (int ks = 0; ks < 4; ++ks) {
    half8 bf[8];
    #pragma unroll
    for (int nt = 0; nt < 8; ++nt)
      bf[nt] = *(const half8*)&xh[(nt * 16 + l15) * 136 + ks * 32 + quad * 8];
    #pragma unroll
    for (int mt = 0; mt < 2; ++mt)
      #pragma unroll
      for (int nt = 0; nt < 8; ++nt)
        acc[mt][nt] = MFMA16(a1[mt][ks], bf[nt], acc[mt][nt]);
  }
  // softmax over d (wave's 32 rows) per column n, then * SCALE
  #pragma unroll
  for (int nt = 0; nt < 8; ++nt) {
    float mx = -1e30f;
    #pragma unroll
    for (int mt = 0; mt < 2; ++mt)
      #pragma unroll
      for (int r = 0; r < 4; ++r) mx = fmaxf(mx, acc[mt][nt][r]);
    mx = fmaxf(mx, __shfl_xor(mx, 16, 64));
    mx = fmaxf(mx, __shfl_xor(mx, 32, 64));
    float sm = 0.f;
    #pragma unroll
    for (int mt = 0; mt < 2; ++mt)
      #pragma unroll
      for (int r = 0; r < 4; ++r) {
        float e = __expf(acc[mt][nt][r] - mx);
        acc[mt][nt][r] = e;
        sm += e;
      }
    sm += __shfl_xor(sm, 16, 64);
    sm += __shfl_xor(sm, 32, 64);
    float sc = SCALEQ / sm;
    #pragma unroll
    for (int mt = 0; mt < 2; ++mt)
      #pragma unroll
      for (int r = 0; r < 4; ++r) acc[mt][nt][r] *= sc;
  }
  __syncthreads();  // all waves done reading xh as x
  // write q_sm -> q_l[n][hd] (same buffer)
  #pragma unroll
  for (int mt = 0; mt < 2; ++mt)
    #pragma unroll
    for (int nt = 0; nt < 8; ++nt) {
      half4 hq;
      #pragma unroll
      for (int r = 0; r < 4; ++r) hq[r] = (_Float16)acc[mt][nt][r];
      *(half4*)&xh[(nt * 16 + l15) * 136 + 32 * wv + mt * 16 + quad * 4] = hq;
    }
  __syncthreads();

  // phase 2: y^T[n][o] = q^T @ C_b^T : per wave M=32 n (strip wv), N=128 o, K=128 hd
  // A = q_l rows (LDS), B = cb rows (global, L2-resident)
  float4v acc2[2][8] = {zero4, zero4, zero4, zero4, zero4, zero4, zero4, zero4,
                        zero4, zero4, zero4, zero4, zero4, zero4, zero4, zero4};
  #pragma unroll
  for (int ks = 0; ks < 4; ++ks) {
    half8 aq[2];
    #pragma unroll
    for (int mt = 0; mt < 2; ++mt)
      aq[mt] = *(const half8*)&xh[(32 * wv + mt * 16 + l15) * 136 +
                                  ks * 32 + quad * 8];
    half8 bc[8];
    #pragma unroll
    for (int nt = 0; nt < 8; ++nt)
      bc[nt] = *(const half8*)(cbg + (nt * 16 + l15) * 128 + ks * 32 + quad * 8);
    #pragma unroll
    for (int mt = 0; mt < 2; ++mt)
      #pragma unroll
      for (int nt = 0; nt < 8; ++nt)
        acc2[mt][nt] = MFMA16(aq[mt], bc[nt], acc2[mt][nt]);
  }

  // epilogue: unscale, +b_out (per-o), LN over o via lane shuffles, float4 stores
  float bo[8], ga[8], be[8];
  #pragma unroll
  for (int nt = 0; nt < 8; ++nt) {
    int o = nt * 16 + l15;
    bo[nt] = b_out[o];
    ga[nt] = gamma[o];
    be[nt] = beta[o];
  }
  #pragma unroll
  for (int mt = 0; mt < 2; ++mt)
    #pragma unroll
    for (int nt = 0; nt < 8; ++nt)
      #pragma unroll
      for (int r = 0; r < 4; ++r)
        acc2[mt][nt][r] = acc2[mt][nt][r] * CB_INV + bo[nt];
  float meanr[2][4], invr[2][4];
  #pragma unroll
  for (int mt = 0; mt < 2; ++mt)
    #pragma unroll
    for (int r = 0; r < 4; ++r) {
      float ps = 0.f, pq = 0.f;
      #pragma unroll
      for (int nt = 0; nt < 8; ++nt) {
        float v = acc2[mt][nt][r];
        ps += v;
        pq += v * v;
      }
      ps += __shfl_xor(ps, 1, 64); pq += __shfl_xor(pq, 1, 64);
      ps += __shfl_xor(ps, 2, 64); pq += __shfl_xor(pq, 2, 64);
      ps += __shfl_xor(ps, 4, 64); pq += __shfl_xor(pq, 4, 64);
      ps += __shfl_xor(ps, 8, 64); pq += __shfl_xor(pq, 8, 64);
      float mean = ps * (1.0f / 128.0f);
      float var = pq * (1.0f / 128.0f) - mean * mean;
      meanr[mt][r] = mean;
      invr[mt][r] = rsqrtf(var + 1e-5f);
    }
  float* ob = out + (size_t)b * 128 * WLEN + n0;
  #pragma unroll
  for (int mt = 0; mt < 2; ++mt)
    #pragma unroll
    for (int nt = 0; nt < 8; ++nt) {
      float4 o4;
      o4.x = (acc2[mt][nt][0] - meanr[mt][0]) * invr[mt][0] * ga[nt] + be[nt];
      o4.y = (acc2[mt][nt][1] - meanr[mt][1]) * invr[mt][1] * ga[nt] + be[nt];
      o4.z = (acc2[mt][nt][2] - meanr[mt][2]) * invr[mt][2] * ga[nt] + be[nt];
      o4.w = (acc2[mt][nt][3] - meanr[mt][3]) * invr[mt][3] * ga[nt] + be[nt];
      *(float4*)(ob + (size_t)(nt * 16 + l15) * WLEN + 32 * wv + mt * 16 +
                 quad * 4) = o4;
    }
}

extern "C" void kernel_launch(void* const* d_in, const int* in_sizes, int n_in,
                              void* d_out, int out_size, void* d_ws, size_t ws_size,
                              hipStream_t stream) {
  const float* x    = (const float*)d_in[0];
  const float* Wqkv = (const float*)d_in[1];
  const float* Wout = (const float*)d_in[2];
  const float* bo   = (const float*)d_in[3];
  const float* gam  = (const float*)d_in[4];
  const float* bet  = (const float*)d_in[5];
  float* out = (float*)d_out;
  float* ws  = (float*)d_ws;

  hipMemsetAsync(ws, 0, (65536 + 2048) * sizeof(float), stream);
  hipLaunchKernelGGL(k0_prep, dim3(192), dim3(256), 0, stream, Wqkv, ws);
  hipLaunchKernelGGL(ka_ctx, dim3(32, 16), dim3(256), 0, stream, x, ws);
  hipLaunchKernelGGL(kb_cb, dim3(16), dim3(256), 0, stream, Wout, ws);
  hipLaunchKernelGGL(kc_out, dim3(128, 16), dim3(256), 0, stream,
                     x, ws, bo, gam, bet, out);
}